// Round 1
// baseline (1794.502 us; speedup 1.0000x reference)
//
#include <hip/hip_runtime.h>
#include <hip/hip_bf16.h>

#define N_NODES 50000
#define N_EDGES 800000

// ---------------------------------------------------------------------------
// GEMM1: support1[50000][96] = x[50000][256] @ W1[256][96]   (f32 vector)
// Block 256 threads, tile 128 rows x 96 cols, BK=32, per-thread 8x6.
// ---------------------------------------------------------------------------
__global__ __launch_bounds__(256) void gemm1_kernel(const float* __restrict__ x,
                                                    const float* __restrict__ W1,
                                                    float* __restrict__ out) {
    __shared__ float xs[128][33];   // +1 pad breaks row-stride bank conflicts
    __shared__ float ws[32][96];
    const int tid = threadIdx.x;
    const int block_row = blockIdx.x * 128;
    const int tc = tid & 15;        // 16 col groups
    const int tr = tid >> 4;        // 16 row groups
    const int c0 = tc * 6;
    const int r0 = tr * 8;
    float acc[8][6];
    #pragma unroll
    for (int i = 0; i < 8; ++i)
        #pragma unroll
        for (int j = 0; j < 6; ++j) acc[i][j] = 0.f;

    const int lr = tid >> 3;          // 0..31
    const int kq = (tid & 7) * 4;     // 0,4,...,28

    for (int k0 = 0; k0 < 256; k0 += 32) {
        // stage x tile 128x32
        #pragma unroll
        for (int it = 0; it < 4; ++it) {
            int row  = lr + it * 32;
            int grow = block_row + row;
            float4 v = make_float4(0.f, 0.f, 0.f, 0.f);
            if (grow < N_NODES)
                v = *reinterpret_cast<const float4*>(&x[(size_t)grow * 256 + k0 + kq]);
            xs[row][kq]     = v.x;
            xs[row][kq + 1] = v.y;
            xs[row][kq + 2] = v.z;
            xs[row][kq + 3] = v.w;
        }
        // stage W chunk 32x96 (contiguous)
        {
            const float4* wsrc = reinterpret_cast<const float4*>(W1 + k0 * 96);
            float4* wdst = reinterpret_cast<float4*>(&ws[0][0]);
            #pragma unroll
            for (int i = 0; i < 3; ++i) wdst[tid + i * 256] = wsrc[tid + i * 256];
        }
        __syncthreads();
        #pragma unroll 4
        for (int kk = 0; kk < 32; ++kk) {
            float a[8], b[6];
            #pragma unroll
            for (int i = 0; i < 8; ++i) a[i] = xs[r0 + i][kk];
            #pragma unroll
            for (int j = 0; j < 6; ++j) b[j] = ws[kk][c0 + j];
            #pragma unroll
            for (int i = 0; i < 8; ++i)
                #pragma unroll
                for (int j = 0; j < 6; ++j) acc[i][j] += a[i] * b[j];
        }
        __syncthreads();
    }
    #pragma unroll
    for (int i = 0; i < 8; ++i) {
        int grow = block_row + r0 + i;
        if (grow < N_NODES) {
            float* o = &out[(size_t)grow * 96 + c0];
            #pragma unroll
            for (int j = 0; j < 6; ++j) o[j] = acc[i][j];
        }
    }
}

// ---------------------------------------------------------------------------
// GEMM2: support2[50000][64] = h1[50000][96] @ W2[96][64]
// Block 256 threads, tile 128 rows x 64 cols, BK=32, per-thread 8x4.
// ---------------------------------------------------------------------------
__global__ __launch_bounds__(256) void gemm2_kernel(const float* __restrict__ h,
                                                    const float* __restrict__ W2,
                                                    float* __restrict__ out) {
    __shared__ float xs[128][33];
    __shared__ float ws[32][64];
    const int tid = threadIdx.x;
    const int block_row = blockIdx.x * 128;
    const int tc = tid & 15;
    const int tr = tid >> 4;
    const int c0 = tc * 4;
    const int r0 = tr * 8;
    float acc[8][4];
    #pragma unroll
    for (int i = 0; i < 8; ++i)
        #pragma unroll
        for (int j = 0; j < 4; ++j) acc[i][j] = 0.f;

    const int lr = tid >> 3;
    const int kq = (tid & 7) * 4;

    for (int k0 = 0; k0 < 96; k0 += 32) {
        #pragma unroll
        for (int it = 0; it < 4; ++it) {
            int row  = lr + it * 32;
            int grow = block_row + row;
            float4 v = make_float4(0.f, 0.f, 0.f, 0.f);
            if (grow < N_NODES)
                v = *reinterpret_cast<const float4*>(&h[(size_t)grow * 96 + k0 + kq]);
            xs[row][kq]     = v.x;
            xs[row][kq + 1] = v.y;
            xs[row][kq + 2] = v.z;
            xs[row][kq + 3] = v.w;
        }
        {
            const float4* wsrc = reinterpret_cast<const float4*>(W2 + k0 * 64);
            float4* wdst = reinterpret_cast<float4*>(&ws[0][0]);
            #pragma unroll
            for (int i = 0; i < 2; ++i) wdst[tid + i * 256] = wsrc[tid + i * 256];
        }
        __syncthreads();
        #pragma unroll 4
        for (int kk = 0; kk < 32; ++kk) {
            float a[8], b[4];
            #pragma unroll
            for (int i = 0; i < 8; ++i) a[i] = xs[r0 + i][kk];
            #pragma unroll
            for (int j = 0; j < 4; ++j) b[j] = ws[kk][c0 + j];
            #pragma unroll
            for (int i = 0; i < 8; ++i)
                #pragma unroll
                for (int j = 0; j < 4; ++j) acc[i][j] += a[i] * b[j];
        }
        __syncthreads();
    }
    #pragma unroll
    for (int i = 0; i < 8; ++i) {
        int grow = block_row + r0 + i;
        if (grow < N_NODES) {
            float4 v = make_float4(acc[i][0], acc[i][1], acc[i][2], acc[i][3]);
            *reinterpret_cast<float4*>(&out[(size_t)grow * 64 + c0]) = v;
        }
    }
}

// ---------------------------------------------------------------------------
// Scatter-add SpMM: agg[dst[e]][:] += support[src[e]][:] * w[e]
// One thread per (edge, 4-channel quad). NQ = DIM/4.
// ---------------------------------------------------------------------------
template <int NQ, int DIM>
__global__ __launch_bounds__(256) void scatter_kernel(const float* __restrict__ sup,
                                                      const int* __restrict__ srcv,
                                                      const int* __restrict__ dstv,
                                                      const float* __restrict__ wv,
                                                      float* __restrict__ agg) {
    unsigned gid = blockIdx.x * 256u + threadIdx.x;
    if (gid >= (unsigned)N_EDGES * NQ) return;
    unsigned e = gid / NQ;          // const divisor -> magic mul
    unsigned q = gid - e * NQ;
    int s = srcv[e];
    int d = dstv[e];
    float wt = wv[e];
    float4 v = *reinterpret_cast<const float4*>(&sup[(size_t)s * DIM + q * 4]);
    float* o = &agg[(size_t)d * DIM + q * 4];
    unsafeAtomicAdd(o + 0, v.x * wt);
    unsafeAtomicAdd(o + 1, v.y * wt);
    unsafeAtomicAdd(o + 2, v.z * wt);
    unsafeAtomicAdd(o + 3, v.w * wt);
}

// ---------------------------------------------------------------------------
// In-place bias + ReLU over [N_NODES][DIM], float4 per thread.
// ---------------------------------------------------------------------------
template <int DIM>
__global__ __launch_bounds__(256) void bias_relu_kernel(float* __restrict__ a,
                                                        const float* __restrict__ b) {
    unsigned gid = blockIdx.x * 256u + threadIdx.x;
    const unsigned total = (unsigned)N_NODES * (DIM / 4);
    if (gid >= total) return;
    unsigned q = gid % (DIM / 4);
    float4 v = reinterpret_cast<float4*>(a)[gid];
    const float4 bb = *reinterpret_cast<const float4*>(&b[q * 4]);
    v.x = fmaxf(v.x + bb.x, 0.f);
    v.y = fmaxf(v.y + bb.y, 0.f);
    v.z = fmaxf(v.z + bb.z, 0.f);
    v.w = fmaxf(v.w + bb.w, 0.f);
    reinterpret_cast<float4*>(a)[gid] = v;
}

// ---------------------------------------------------------------------------
// Column-sum of relu(agg2 + b2) over all nodes -> pooled[64] (atomic per block)
// ---------------------------------------------------------------------------
__global__ __launch_bounds__(256) void colsum_kernel(const float* __restrict__ agg2,
                                                     const float* __restrict__ b2,
                                                     float* __restrict__ pooled) {
    __shared__ float red[4][64];
    const int t = threadIdx.x;
    const int c = t & 63, r = t >> 6;
    const float bc = b2[c];
    float s = 0.f;
    const int base = blockIdx.x * 256;
    for (int i = r; i < 256; i += 4) {
        int n = base + i;
        if (n < N_NODES) {
            float v = agg2[(size_t)n * 64 + c] + bc;
            s += fmaxf(v, 0.f);
        }
    }
    red[r][c] = s;
    __syncthreads();
    if (r == 0) {
        float v = red[0][c] + red[1][c] + red[2][c] + red[3][c];
        unsafeAtomicAdd(&pooled[c], v);
    }
}

// ---------------------------------------------------------------------------
// Final: selu(pooled/N) + 0.5*(sub_fea @ fc_w^T + fc_b) -> log_softmax -> out
// Single wave of 64 threads.
// ---------------------------------------------------------------------------
__global__ void final_kernel(const float* __restrict__ pooled,
                             const float* __restrict__ sub_fea,
                             const float* __restrict__ fc_w,
                             const float* __restrict__ fc_b,
                             float* __restrict__ out) {
    const int c = threadIdx.x;  // 0..63
    float p = pooled[c] * (1.0f / (float)N_NODES);
    const float kScale = 1.0507009873554805f;
    const float kAlpha = 1.6732632423543772f;
    float se = (p > 0.f) ? kScale * p : kScale * kAlpha * (expf(p) - 1.f);
    float xe = fc_b[c];
    for (int k = 0; k < 128; ++k) xe += sub_fea[k] * fc_w[c * 128 + k];
    float v = se + 0.5f * xe;
    float m = v;
    #pragma unroll
    for (int off = 32; off >= 1; off >>= 1) m = fmaxf(m, __shfl_xor(m, off));
    float ex = expf(v - m);
    float ss = ex;
    #pragma unroll
    for (int off = 32; off >= 1; off >>= 1) ss += __shfl_xor(ss, off);
    out[c] = v - m - logf(ss);
}

// ---------------------------------------------------------------------------
extern "C" void kernel_launch(void* const* d_in, const int* in_sizes, int n_in,
                              void* d_out, int out_size, void* d_ws, size_t ws_size,
                              hipStream_t stream) {
    const float* x       = (const float*)d_in[0];
    const int*   ei      = (const int*)d_in[1];   // [2][E]: src row 0, dst row 1
    const float* ew      = (const float*)d_in[2];
    const float* sub_fea = (const float*)d_in[3];
    const float* W1      = (const float*)d_in[4];
    const float* b1      = (const float*)d_in[5];
    const float* W2      = (const float*)d_in[6];
    const float* b2      = (const float*)d_in[7];
    const float* fc_w    = (const float*)d_in[8];
    const float* fc_b    = (const float*)d_in[9];
    float* out = (float*)d_out;

    float* ws       = (float*)d_ws;
    float* support1 = ws;                      // 50000*96 = 4,800,000
    float* agg1     = support1 + 4800000;      // 4,800,000 (becomes h1 in place)
    float* support2 = agg1 + 4800000;          // 3,200,000
    float* agg2     = support2 + 3200000;      // 3,200,000
    float* pooled   = agg2 + 3200000;          // 64

    const int* srcv = ei;
    const int* dstv = ei + N_EDGES;

    hipMemsetAsync(agg1, 0, (size_t)4800000 * 4, stream);
    hipMemsetAsync(agg2, 0, (size_t)3200000 * 4, stream);
    hipMemsetAsync(pooled, 0, 64 * 4, stream);

    // Layer 1
    gemm1_kernel<<<(N_NODES + 127) / 128, 256, 0, stream>>>(x, W1, support1);
    {
        unsigned total = (unsigned)N_EDGES * 24;
        scatter_kernel<24, 96><<<(total + 255) / 256, 256, 0, stream>>>(
            support1, srcv, dstv, ew, agg1);
    }
    {
        unsigned total = (unsigned)N_NODES * 24;
        bias_relu_kernel<96><<<(total + 255) / 256, 256, 0, stream>>>(agg1, b1);
    }

    // Layer 2
    gemm2_kernel<<<(N_NODES + 127) / 128, 256, 0, stream>>>(agg1, W2, support2);
    {
        unsigned total = (unsigned)N_EDGES * 16;
        scatter_kernel<16, 64><<<(total + 255) / 256, 256, 0, stream>>>(
            support2, srcv, dstv, ew, agg2);
    }

    // Pool + head
    colsum_kernel<<<(N_NODES + 255) / 256, 256, 0, stream>>>(agg2, b2, pooled);
    final_kernel<<<1, 64, 0, stream>>>(pooled, sub_fea, fc_w, fc_b, out);
}

// Round 2
// 382.523 us; speedup vs baseline: 4.6912x; 4.6912x over previous
//
#include <hip/hip_runtime.h>
#include <hip/hip_bf16.h>

#define N_NODES 50000
#define N_EDGES 800000

// ---------------------------------------------------------------------------
// GEMM1: support1[50000][96] = x[50000][256] @ W1[256][96]   (f32 vector)
// ---------------------------------------------------------------------------
__global__ __launch_bounds__(256) void gemm1_kernel(const float* __restrict__ x,
                                                    const float* __restrict__ W1,
                                                    float* __restrict__ out) {
    __shared__ float xs[128][33];
    __shared__ float ws[32][96];
    const int tid = threadIdx.x;
    const int block_row = blockIdx.x * 128;
    const int tc = tid & 15;
    const int tr = tid >> 4;
    const int c0 = tc * 6;
    const int r0 = tr * 8;
    float acc[8][6];
    #pragma unroll
    for (int i = 0; i < 8; ++i)
        #pragma unroll
        for (int j = 0; j < 6; ++j) acc[i][j] = 0.f;

    const int lr = tid >> 3;
    const int kq = (tid & 7) * 4;

    for (int k0 = 0; k0 < 256; k0 += 32) {
        #pragma unroll
        for (int it = 0; it < 4; ++it) {
            int row  = lr + it * 32;
            int grow = block_row + row;
            float4 v = make_float4(0.f, 0.f, 0.f, 0.f);
            if (grow < N_NODES)
                v = *reinterpret_cast<const float4*>(&x[(size_t)grow * 256 + k0 + kq]);
            xs[row][kq]     = v.x;
            xs[row][kq + 1] = v.y;
            xs[row][kq + 2] = v.z;
            xs[row][kq + 3] = v.w;
        }
        {
            const float4* wsrc = reinterpret_cast<const float4*>(W1 + k0 * 96);
            float4* wdst = reinterpret_cast<float4*>(&ws[0][0]);
            #pragma unroll
            for (int i = 0; i < 3; ++i) wdst[tid + i * 256] = wsrc[tid + i * 256];
        }
        __syncthreads();
        #pragma unroll 4
        for (int kk = 0; kk < 32; ++kk) {
            float a[8], b[6];
            #pragma unroll
            for (int i = 0; i < 8; ++i) a[i] = xs[r0 + i][kk];
            #pragma unroll
            for (int j = 0; j < 6; ++j) b[j] = ws[kk][c0 + j];
            #pragma unroll
            for (int i = 0; i < 8; ++i)
                #pragma unroll
                for (int j = 0; j < 6; ++j) acc[i][j] += a[i] * b[j];
        }
        __syncthreads();
    }
    #pragma unroll
    for (int i = 0; i < 8; ++i) {
        int grow = block_row + r0 + i;
        if (grow < N_NODES) {
            float* o = &out[(size_t)grow * 96 + c0];
            #pragma unroll
            for (int j = 0; j < 6; ++j) o[j] = acc[i][j];
        }
    }
}

// ---------------------------------------------------------------------------
// GEMM2: support2[50000][64] = h1[50000][96] @ W2[96][64]
// ---------------------------------------------------------------------------
__global__ __launch_bounds__(256) void gemm2_kernel(const float* __restrict__ h,
                                                    const float* __restrict__ W2,
                                                    float* __restrict__ out) {
    __shared__ float xs[128][33];
    __shared__ float ws[32][64];
    const int tid = threadIdx.x;
    const int block_row = blockIdx.x * 128;
    const int tc = tid & 15;
    const int tr = tid >> 4;
    const int c0 = tc * 4;
    const int r0 = tr * 8;
    float acc[8][4];
    #pragma unroll
    for (int i = 0; i < 8; ++i)
        #pragma unroll
        for (int j = 0; j < 4; ++j) acc[i][j] = 0.f;

    const int lr = tid >> 3;
    const int kq = (tid & 7) * 4;

    for (int k0 = 0; k0 < 96; k0 += 32) {
        #pragma unroll
        for (int it = 0; it < 4; ++it) {
            int row  = lr + it * 32;
            int grow = block_row + row;
            float4 v = make_float4(0.f, 0.f, 0.f, 0.f);
            if (grow < N_NODES)
                v = *reinterpret_cast<const float4*>(&h[(size_t)grow * 96 + k0 + kq]);
            xs[row][kq]     = v.x;
            xs[row][kq + 1] = v.y;
            xs[row][kq + 2] = v.z;
            xs[row][kq + 3] = v.w;
        }
        {
            const float4* wsrc = reinterpret_cast<const float4*>(W2 + k0 * 64);
            float4* wdst = reinterpret_cast<float4*>(&ws[0][0]);
            #pragma unroll
            for (int i = 0; i < 2; ++i) wdst[tid + i * 256] = wsrc[tid + i * 256];
        }
        __syncthreads();
        #pragma unroll 4
        for (int kk = 0; kk < 32; ++kk) {
            float a[8], b[4];
            #pragma unroll
            for (int i = 0; i < 8; ++i) a[i] = xs[r0 + i][kk];
            #pragma unroll
            for (int j = 0; j < 4; ++j) b[j] = ws[kk][c0 + j];
            #pragma unroll
            for (int i = 0; i < 8; ++i)
                #pragma unroll
                for (int j = 0; j < 4; ++j) acc[i][j] += a[i] * b[j];
        }
        __syncthreads();
    }
    #pragma unroll
    for (int i = 0; i < 8; ++i) {
        int grow = block_row + r0 + i;
        if (grow < N_NODES) {
            float4 v = make_float4(acc[i][0], acc[i][1], acc[i][2], acc[i][3]);
            *reinterpret_cast<float4*>(&out[(size_t)grow * 64 + c0]) = v;
        }
    }
}

// ---------------------------------------------------------------------------
// CSR build step 1: histogram of dst
// ---------------------------------------------------------------------------
__global__ __launch_bounds__(256) void hist_kernel(const int* __restrict__ dstv,
                                                   int* __restrict__ cnt) {
    int e = blockIdx.x * 256 + threadIdx.x;
    if (e < N_EDGES) atomicAdd(&cnt[dstv[e]], 1);
}

// ---------------------------------------------------------------------------
// CSR build step 2: exclusive scan of cnt[50000] -> off[50001]; rewrite cnt
// in place as the running cursor (cnt may alias cur). Single 1024-thread block.
// ---------------------------------------------------------------------------
__global__ __launch_bounds__(1024) void scan_kernel(int* __restrict__ cnt,
                                                    int* __restrict__ off) {
    __shared__ int part[1024];
    const int t = threadIdx.x;
    const int chunk = (N_NODES + 1023) / 1024;  // 49
    const int start = t * chunk;
    const int end = min(start + chunk, N_NODES);
    int s = 0;
    for (int i = start; i < end; ++i) s += cnt[i];
    part[t] = s;
    __syncthreads();
    #pragma unroll
    for (int d = 1; d < 1024; d <<= 1) {
        int v = (t >= d) ? part[t - d] : 0;
        __syncthreads();
        part[t] += v;
        __syncthreads();
    }
    int run = (t == 0) ? 0 : part[t - 1];
    for (int i = start; i < end; ++i) {
        int c = cnt[i];          // read BEFORE overwrite (cnt is rewritten as cursor)
        off[i] = run;
        cnt[i] = run;            // cursor init
        run += c;
    }
    if (t == 1023) off[N_NODES] = part[1023];
}

// ---------------------------------------------------------------------------
// CSR build step 3: fill packed (src, weight_bits) per edge, grouped by dst.
// ---------------------------------------------------------------------------
__global__ __launch_bounds__(256) void fill_kernel(const int* __restrict__ srcv,
                                                   const int* __restrict__ dstv,
                                                   const float* __restrict__ wv,
                                                   int* __restrict__ cur,
                                                   int2* __restrict__ ewp) {
    int e = blockIdx.x * 256 + threadIdx.x;
    if (e >= N_EDGES) return;
    int d = dstv[e];
    int pos = atomicAdd(&cur[d], 1);
    ewp[pos] = make_int2(srcv[e], __float_as_int(wv[e]));
}

// ---------------------------------------------------------------------------
// Gather aggregation: out[n][:] = relu( sum_{e in row n} sup[src_e]*w_e + b )
// One thread per (node, channel-quad).
// ---------------------------------------------------------------------------
template <int DIM>
__global__ __launch_bounds__(256) void gather_agg_kernel(const float* __restrict__ sup,
                                                         const int* __restrict__ off,
                                                         const int2* __restrict__ ewp,
                                                         const float* __restrict__ bias,
                                                         float* __restrict__ outp) {
    const int NQ = DIM / 4;
    unsigned gid = blockIdx.x * 256u + threadIdx.x;
    if (gid >= (unsigned)N_NODES * NQ) return;
    unsigned n = gid / NQ;           // const divisor -> magic mul
    unsigned q = gid - n * NQ;
    const int e0 = off[n], e1 = off[n + 1];
    float4 acc = make_float4(0.f, 0.f, 0.f, 0.f);
    for (int e = e0; e < e1; ++e) {
        int2 p = ewp[e];             // broadcast across quads of this node
        float w = __int_as_float(p.y);
        float4 v = *reinterpret_cast<const float4*>(&sup[(size_t)p.x * DIM + q * 4]);
        acc.x += v.x * w;
        acc.y += v.y * w;
        acc.z += v.z * w;
        acc.w += v.w * w;
    }
    const float4 bb = *reinterpret_cast<const float4*>(&bias[q * 4]);
    acc.x = fmaxf(acc.x + bb.x, 0.f);
    acc.y = fmaxf(acc.y + bb.y, 0.f);
    acc.z = fmaxf(acc.z + bb.z, 0.f);
    acc.w = fmaxf(acc.w + bb.w, 0.f);
    *reinterpret_cast<float4*>(&outp[(size_t)n * DIM + q * 4]) = acc;
}

// ---------------------------------------------------------------------------
// Column-sum of h2 (already bias+relu'd) over all nodes -> pooled[64]
// ---------------------------------------------------------------------------
__global__ __launch_bounds__(256) void colsum_kernel(const float* __restrict__ h2,
                                                     float* __restrict__ pooled) {
    __shared__ float red[4][64];
    const int t = threadIdx.x;
    const int c = t & 63, r = t >> 6;
    float s = 0.f;
    const int base = blockIdx.x * 256;
    for (int i = r; i < 256; i += 4) {
        int n = base + i;
        if (n < N_NODES) s += h2[(size_t)n * 64 + c];
    }
    red[r][c] = s;
    __syncthreads();
    if (r == 0) {
        float v = red[0][c] + red[1][c] + red[2][c] + red[3][c];
        unsafeAtomicAdd(&pooled[c], v);
    }
}

// ---------------------------------------------------------------------------
// Final head: selu(pooled/N) + 0.5*(sub_fea @ fc_w^T + fc_b) -> log_softmax
// ---------------------------------------------------------------------------
__global__ void final_kernel(const float* __restrict__ pooled,
                             const float* __restrict__ sub_fea,
                             const float* __restrict__ fc_w,
                             const float* __restrict__ fc_b,
                             float* __restrict__ out) {
    const int c = threadIdx.x;  // 0..63
    float p = pooled[c] * (1.0f / (float)N_NODES);
    const float kScale = 1.0507009873554805f;
    const float kAlpha = 1.6732632423543772f;
    float se = (p > 0.f) ? kScale * p : kScale * kAlpha * (expf(p) - 1.f);
    float xe = fc_b[c];
    for (int k = 0; k < 128; ++k) xe += sub_fea[k] * fc_w[c * 128 + k];
    float v = se + 0.5f * xe;
    float m = v;
    #pragma unroll
    for (int off = 32; off >= 1; off >>= 1) m = fmaxf(m, __shfl_xor(m, off));
    float ex = expf(v - m);
    float ss = ex;
    #pragma unroll
    for (int off = 32; off >= 1; off >>= 1) ss += __shfl_xor(ss, off);
    out[c] = v - m - logf(ss);
}

// ---------------------------------------------------------------------------
extern "C" void kernel_launch(void* const* d_in, const int* in_sizes, int n_in,
                              void* d_out, int out_size, void* d_ws, size_t ws_size,
                              hipStream_t stream) {
    const float* x       = (const float*)d_in[0];
    const int*   ei      = (const int*)d_in[1];   // [2][E]: src row 0, dst row 1
    const float* ew      = (const float*)d_in[2];
    const float* sub_fea = (const float*)d_in[3];
    const float* W1      = (const float*)d_in[4];
    const float* b1      = (const float*)d_in[5];
    const float* W2      = (const float*)d_in[6];
    const float* b2      = (const float*)d_in[7];
    const float* fc_w    = (const float*)d_in[8];
    const float* fc_b    = (const float*)d_in[9];
    float* out = (float*)d_out;

    // Workspace layout (bytes). A reused: support1 then support2. B: h1 then h2.
    char* base = (char*)d_ws;
    float* A      = (float*)(base);                 // 4.8M floats (19.2 MB)
    float* B      = (float*)(base + 19200000);      // 4.8M floats (19.2 MB)
    float* pooled = (float*)(base + 38400000);      // 64 floats
    int*   off    = (int*)  (base + 38400512);      // 50001 ints
    int*   cur    = (int*)  (base + 38600960);      // 50000 ints (count->cursor)
    int2*  ewp    = (int2*) (base + 38801408);      // 800000 int2 (6.4 MB)

    const int* srcv = ei;
    const int* dstv = ei + N_EDGES;

    // ---- CSR build (shared by both layers) ----
    hipMemsetAsync(cur, 0, N_NODES * 4, stream);
    hipMemsetAsync(pooled, 0, 64 * 4, stream);
    hist_kernel<<<(N_EDGES + 255) / 256, 256, 0, stream>>>(dstv, cur);
    scan_kernel<<<1, 1024, 0, stream>>>(cur, off);   // cnt -> off, cnt becomes cursor
    fill_kernel<<<(N_EDGES + 255) / 256, 256, 0, stream>>>(srcv, dstv, ew, cur, ewp);

    // ---- Layer 1 ----
    gemm1_kernel<<<(N_NODES + 127) / 128, 256, 0, stream>>>(x, W1, A);
    {
        unsigned total = (unsigned)N_NODES * 24;
        gather_agg_kernel<96><<<(total + 255) / 256, 256, 0, stream>>>(A, off, ewp, b1, B);
    }

    // ---- Layer 2 ----
    gemm2_kernel<<<(N_NODES + 127) / 128, 256, 0, stream>>>(B, W2, A);
    {
        unsigned total = (unsigned)N_NODES * 16;
        gather_agg_kernel<64><<<(total + 255) / 256, 256, 0, stream>>>(A, off, ewp, b2, B);
    }

    // ---- Pool + head ----
    colsum_kernel<<<(N_NODES + 255) / 256, 256, 0, stream>>>(B, pooled);
    final_kernel<<<1, 64, 0, stream>>>(pooled, sub_fea, fc_w, fc_b, out);
}

// Round 3
// 284.630 us; speedup vs baseline: 6.3047x; 1.3439x over previous
//
#include <hip/hip_runtime.h>
#include <hip/hip_bf16.h>

#define N_NODES 50000
#define N_EDGES 800000
#define SCAN_NBLK ((N_NODES + 255) / 256)   // 196

// ---------------------------------------------------------------------------
// GEMM1: support1[50000][96] = x[50000][256] @ W1[256][96]   (f32 vector)
// ---------------------------------------------------------------------------
__global__ __launch_bounds__(256) void gemm1_kernel(const float* __restrict__ x,
                                                    const float* __restrict__ W1,
                                                    float* __restrict__ out) {
    __shared__ float xs[128][33];
    __shared__ float ws[32][96];
    const int tid = threadIdx.x;
    const int block_row = blockIdx.x * 128;
    const int tc = tid & 15;
    const int tr = tid >> 4;
    const int c0 = tc * 6;
    const int r0 = tr * 8;
    float acc[8][6];
    #pragma unroll
    for (int i = 0; i < 8; ++i)
        #pragma unroll
        for (int j = 0; j < 6; ++j) acc[i][j] = 0.f;

    const int lr = tid >> 3;
    const int kq = (tid & 7) * 4;

    for (int k0 = 0; k0 < 256; k0 += 32) {
        #pragma unroll
        for (int it = 0; it < 4; ++it) {
            int row  = lr + it * 32;
            int grow = block_row + row;
            float4 v = make_float4(0.f, 0.f, 0.f, 0.f);
            if (grow < N_NODES)
                v = *reinterpret_cast<const float4*>(&x[(size_t)grow * 256 + k0 + kq]);
            xs[row][kq]     = v.x;
            xs[row][kq + 1] = v.y;
            xs[row][kq + 2] = v.z;
            xs[row][kq + 3] = v.w;
        }
        {
            const float4* wsrc = reinterpret_cast<const float4*>(W1 + k0 * 96);
            float4* wdst = reinterpret_cast<float4*>(&ws[0][0]);
            #pragma unroll
            for (int i = 0; i < 3; ++i) wdst[tid + i * 256] = wsrc[tid + i * 256];
        }
        __syncthreads();
        #pragma unroll 4
        for (int kk = 0; kk < 32; ++kk) {
            float a[8], b[6];
            #pragma unroll
            for (int i = 0; i < 8; ++i) a[i] = xs[r0 + i][kk];
            #pragma unroll
            for (int j = 0; j < 6; ++j) b[j] = ws[kk][c0 + j];
            #pragma unroll
            for (int i = 0; i < 8; ++i)
                #pragma unroll
                for (int j = 0; j < 6; ++j) acc[i][j] += a[i] * b[j];
        }
        __syncthreads();
    }
    #pragma unroll
    for (int i = 0; i < 8; ++i) {
        int grow = block_row + r0 + i;
        if (grow < N_NODES) {
            float* o = &out[(size_t)grow * 96 + c0];
            #pragma unroll
            for (int j = 0; j < 6; ++j) o[j] = acc[i][j];
        }
    }
}

// ---------------------------------------------------------------------------
// GEMM2: support2[50000][64] = h1[50000][96] @ W2[96][64]
// ---------------------------------------------------------------------------
__global__ __launch_bounds__(256) void gemm2_kernel(const float* __restrict__ h,
                                                    const float* __restrict__ W2,
                                                    float* __restrict__ out) {
    __shared__ float xs[128][33];
    __shared__ float ws[32][64];
    const int tid = threadIdx.x;
    const int block_row = blockIdx.x * 128;
    const int tc = tid & 15;
    const int tr = tid >> 4;
    const int c0 = tc * 4;
    const int r0 = tr * 8;
    float acc[8][4];
    #pragma unroll
    for (int i = 0; i < 8; ++i)
        #pragma unroll
        for (int j = 0; j < 4; ++j) acc[i][j] = 0.f;

    const int lr = tid >> 3;
    const int kq = (tid & 7) * 4;

    for (int k0 = 0; k0 < 96; k0 += 32) {
        #pragma unroll
        for (int it = 0; it < 4; ++it) {
            int row  = lr + it * 32;
            int grow = block_row + row;
            float4 v = make_float4(0.f, 0.f, 0.f, 0.f);
            if (grow < N_NODES)
                v = *reinterpret_cast<const float4*>(&h[(size_t)grow * 96 + k0 + kq]);
            xs[row][kq]     = v.x;
            xs[row][kq + 1] = v.y;
            xs[row][kq + 2] = v.z;
            xs[row][kq + 3] = v.w;
        }
        {
            const float4* wsrc = reinterpret_cast<const float4*>(W2 + k0 * 64);
            float4* wdst = reinterpret_cast<float4*>(&ws[0][0]);
            #pragma unroll
            for (int i = 0; i < 2; ++i) wdst[tid + i * 256] = wsrc[tid + i * 256];
        }
        __syncthreads();
        #pragma unroll 4
        for (int kk = 0; kk < 32; ++kk) {
            float a[8], b[4];
            #pragma unroll
            for (int i = 0; i < 8; ++i) a[i] = xs[r0 + i][kk];
            #pragma unroll
            for (int j = 0; j < 4; ++j) b[j] = ws[kk][c0 + j];
            #pragma unroll
            for (int i = 0; i < 8; ++i)
                #pragma unroll
                for (int j = 0; j < 4; ++j) acc[i][j] += a[i] * b[j];
        }
        __syncthreads();
    }
    #pragma unroll
    for (int i = 0; i < 8; ++i) {
        int grow = block_row + r0 + i;
        if (grow < N_NODES) {
            float4 v = make_float4(acc[i][0], acc[i][1], acc[i][2], acc[i][3]);
            *reinterpret_cast<float4*>(&out[(size_t)grow * 64 + c0]) = v;
        }
    }
}

// ---------------------------------------------------------------------------
// CSR build step 1: histogram of dst
// ---------------------------------------------------------------------------
__global__ __launch_bounds__(256) void hist_kernel(const int* __restrict__ dstv,
                                                   int* __restrict__ cnt) {
    int e = blockIdx.x * 256 + threadIdx.x;
    if (e < N_EDGES) atomicAdd(&cnt[dstv[e]], 1);
}

// ---------------------------------------------------------------------------
// Multi-block exclusive scan of cnt[50000] -> off[50001] (+ cursor copy).
// scan1: per-block sums. scan2: scan of 196 block sums. scan3: local scan+add.
// ---------------------------------------------------------------------------
__global__ __launch_bounds__(256) void scan1_kernel(const int* __restrict__ cnt,
                                                    int* __restrict__ bsum) {
    __shared__ int red[256];
    const int t = threadIdx.x;
    const int i = blockIdx.x * 256 + t;
    red[t] = (i < N_NODES) ? cnt[i] : 0;
    __syncthreads();
    #pragma unroll
    for (int d = 128; d > 0; d >>= 1) {
        if (t < d) red[t] += red[t + d];
        __syncthreads();
    }
    if (t == 0) bsum[blockIdx.x] = red[0];
}

__global__ __launch_bounds__(256) void scan2_kernel(int* __restrict__ bsum) {
    __shared__ int sh[256];
    const int t = threadIdx.x;
    int v = (t < SCAN_NBLK) ? bsum[t] : 0;
    sh[t] = v;
    __syncthreads();
    #pragma unroll
    for (int d = 1; d < 256; d <<= 1) {
        int u = (t >= d) ? sh[t - d] : 0;
        __syncthreads();
        sh[t] += u;
        __syncthreads();
    }
    if (t < SCAN_NBLK) bsum[t] = sh[t] - v;   // exclusive prefix of block sums
}

__global__ __launch_bounds__(256) void scan3_kernel(const int* __restrict__ cnt,
                                                    const int* __restrict__ bsum,
                                                    int* __restrict__ off,
                                                    int* __restrict__ cur) {
    __shared__ int sh[256];
    const int t = threadIdx.x;
    const int i = blockIdx.x * 256 + t;
    int v = (i < N_NODES) ? cnt[i] : 0;
    sh[t] = v;
    __syncthreads();
    #pragma unroll
    for (int d = 1; d < 256; d <<= 1) {
        int u = (t >= d) ? sh[t - d] : 0;
        __syncthreads();
        sh[t] += u;
        __syncthreads();
    }
    int excl = sh[t] - v + bsum[blockIdx.x];
    if (i < N_NODES) {
        off[i] = excl;
        cur[i] = excl;
    }
    if (i == N_NODES - 1) off[N_NODES] = excl + v;   // = N_EDGES
}

// ---------------------------------------------------------------------------
// CSR build step 3: fill packed (src, weight_bits) per edge, grouped by dst.
// ---------------------------------------------------------------------------
__global__ __launch_bounds__(256) void fill_kernel(const int* __restrict__ srcv,
                                                   const int* __restrict__ dstv,
                                                   const float* __restrict__ wv,
                                                   int* __restrict__ cur,
                                                   int2* __restrict__ ewp) {
    int e = blockIdx.x * 256 + threadIdx.x;
    if (e >= N_EDGES) return;
    int d = dstv[e];
    int pos = atomicAdd(&cur[d], 1);
    ewp[pos] = make_int2(srcv[e], __float_as_int(wv[e]));
}

// ---------------------------------------------------------------------------
// Gather aggregation: out[n][:] = relu( sum_{e in row n} sup[src_e]*w_e + b )
// One thread per (node, channel-quad).
// ---------------------------------------------------------------------------
template <int DIM>
__global__ __launch_bounds__(256) void gather_agg_kernel(const float* __restrict__ sup,
                                                         const int* __restrict__ off,
                                                         const int2* __restrict__ ewp,
                                                         const float* __restrict__ bias,
                                                         float* __restrict__ outp) {
    const int NQ = DIM / 4;
    unsigned gid = blockIdx.x * 256u + threadIdx.x;
    if (gid >= (unsigned)N_NODES * NQ) return;
    unsigned n = gid / NQ;           // const divisor -> magic mul
    unsigned q = gid - n * NQ;
    const int e0 = off[n], e1 = off[n + 1];
    float4 acc = make_float4(0.f, 0.f, 0.f, 0.f);
    for (int e = e0; e < e1; ++e) {
        int2 p = ewp[e];             // broadcast across quads of this node
        float w = __int_as_float(p.y);
        float4 v = *reinterpret_cast<const float4*>(&sup[(size_t)p.x * DIM + q * 4]);
        acc.x += v.x * w;
        acc.y += v.y * w;
        acc.z += v.z * w;
        acc.w += v.w * w;
    }
    const float4 bb = *reinterpret_cast<const float4*>(&bias[q * 4]);
    acc.x = fmaxf(acc.x + bb.x, 0.f);
    acc.y = fmaxf(acc.y + bb.y, 0.f);
    acc.z = fmaxf(acc.z + bb.z, 0.f);
    acc.w = fmaxf(acc.w + bb.w, 0.f);
    *reinterpret_cast<float4*>(&outp[(size_t)n * DIM + q * 4]) = acc;
}

// ---------------------------------------------------------------------------
// Column-sum of h2 (already bias+relu'd) over all nodes -> pooled[64]
// ---------------------------------------------------------------------------
__global__ __launch_bounds__(256) void colsum_kernel(const float* __restrict__ h2,
                                                     float* __restrict__ pooled) {
    __shared__ float red[4][64];
    const int t = threadIdx.x;
    const int c = t & 63, r = t >> 6;
    float s = 0.f;
    const int base = blockIdx.x * 256;
    for (int i = r; i < 256; i += 4) {
        int n = base + i;
        if (n < N_NODES) s += h2[(size_t)n * 64 + c];
    }
    red[r][c] = s;
    __syncthreads();
    if (r == 0) {
        float v = red[0][c] + red[1][c] + red[2][c] + red[3][c];
        unsafeAtomicAdd(&pooled[c], v);
    }
}

// ---------------------------------------------------------------------------
// Final head: selu(pooled/N) + 0.5*(sub_fea @ fc_w^T + fc_b) -> log_softmax
// ---------------------------------------------------------------------------
__global__ void final_kernel(const float* __restrict__ pooled,
                             const float* __restrict__ sub_fea,
                             const float* __restrict__ fc_w,
                             const float* __restrict__ fc_b,
                             float* __restrict__ out) {
    const int c = threadIdx.x;  // 0..63
    float p = pooled[c] * (1.0f / (float)N_NODES);
    const float kScale = 1.0507009873554805f;
    const float kAlpha = 1.6732632423543772f;
    float se = (p > 0.f) ? kScale * p : kScale * kAlpha * (expf(p) - 1.f);
    float xe = fc_b[c];
    for (int k = 0; k < 128; ++k) xe += sub_fea[k] * fc_w[c * 128 + k];
    float v = se + 0.5f * xe;
    float m = v;
    #pragma unroll
    for (int off = 32; off >= 1; off >>= 1) m = fmaxf(m, __shfl_xor(m, off));
    float ex = expf(v - m);
    float ss = ex;
    #pragma unroll
    for (int off = 32; off >= 1; off >>= 1) ss += __shfl_xor(ss, off);
    out[c] = v - m - logf(ss);
}

// ---------------------------------------------------------------------------
extern "C" void kernel_launch(void* const* d_in, const int* in_sizes, int n_in,
                              void* d_out, int out_size, void* d_ws, size_t ws_size,
                              hipStream_t stream) {
    const float* x       = (const float*)d_in[0];
    const int*   ei      = (const int*)d_in[1];   // [2][E]: src row 0, dst row 1
    const float* ew      = (const float*)d_in[2];
    const float* sub_fea = (const float*)d_in[3];
    const float* W1      = (const float*)d_in[4];
    const float* b1      = (const float*)d_in[5];
    const float* W2      = (const float*)d_in[6];
    const float* b2      = (const float*)d_in[7];
    const float* fc_w    = (const float*)d_in[8];
    const float* fc_b    = (const float*)d_in[9];
    float* out = (float*)d_out;

    // Workspace layout (bytes). A reused: support1 then support2. B: h1 then h2.
    char* base = (char*)d_ws;
    float* A      = (float*)(base);                 // 4.8M floats (19.2 MB)
    float* B      = (float*)(base + 19200000);      // 4.8M floats (19.2 MB)
    float* pooled = (float*)(base + 38400000);      // 64 floats
    int*   off    = (int*)  (base + 38400512);      // 50001 ints
    int*   cnt    = (int*)  (base + 38600960);      // 50000 ints
    int*   cur    = (int*)  (base + 38801408);      // 50000 ints
    int*   bsum   = (int*)  (base + 39001856);      // 256 ints
    int2*  ewp    = (int2*) (base + 39002880);      // 800000 int2 (6.4 MB)

    const int* srcv = ei;
    const int* dstv = ei + N_EDGES;

    // ---- CSR build (shared by both layers) ----
    hipMemsetAsync(cnt, 0, N_NODES * 4, stream);
    hipMemsetAsync(pooled, 0, 64 * 4, stream);
    hist_kernel<<<(N_EDGES + 255) / 256, 256, 0, stream>>>(dstv, cnt);
    scan1_kernel<<<SCAN_NBLK, 256, 0, stream>>>(cnt, bsum);
    scan2_kernel<<<1, 256, 0, stream>>>(bsum);
    scan3_kernel<<<SCAN_NBLK, 256, 0, stream>>>(cnt, bsum, off, cur);
    fill_kernel<<<(N_EDGES + 255) / 256, 256, 0, stream>>>(srcv, dstv, ew, cur, ewp);

    // ---- Layer 1 ----
    gemm1_kernel<<<(N_NODES + 127) / 128, 256, 0, stream>>>(x, W1, A);
    {
        unsigned total = (unsigned)N_NODES * 24;
        gather_agg_kernel<96><<<(total + 255) / 256, 256, 0, stream>>>(A, off, ewp, b1, B);
    }

    // ---- Layer 2 ----
    gemm2_kernel<<<(N_NODES + 127) / 128, 256, 0, stream>>>(B, W2, A);
    {
        unsigned total = (unsigned)N_NODES * 16;
        gather_agg_kernel<64><<<(total + 255) / 256, 256, 0, stream>>>(A, off, ewp, b2, B);
    }

    // ---- Pool + head ----
    colsum_kernel<<<(N_NODES + 255) / 256, 256, 0, stream>>>(B, pooled);
    final_kernel<<<1, 64, 0, stream>>>(pooled, sub_fea, fc_w, fc_b, out);
}